// Round 11
// baseline (2374.520 us; speedup 1.0000x reference)
//
#include <hip/hip_runtime.h>

// Graphormer encoder as ONE persistent megakernel (plain launch, software grid
// barrier — no cooperative API). 512 blocks @ __launch_bounds__(256,2) => all
// co-resident. Stage bodies are R8's proven kernels. Attention block-diagonal.

#define NG   64
#define NP   31
#define NORI 1984
#define NT   2048
#define DIM  512
#define NHD  8
#define DKH  64
#define FFD  2048
#define NLAY 4
#define NFEA 32

#define NBLK 512

typedef __attribute__((ext_vector_type(8))) short short8;
typedef __attribute__((ext_vector_type(4))) float floatx4;

__device__ __forceinline__ unsigned short f2bf(float f) {
    union { float f; unsigned u; } v; v.f = f;
    unsigned r = v.u + 0x7fffu + ((v.u >> 16) & 1u);
    return (unsigned short)(r >> 16);
}
__device__ __forceinline__ float bf2f(unsigned short u) {
    union { unsigned u; float f; } v; v.u = ((unsigned)u) << 16;
    return v.f;
}

struct MP {
    const float* x; const int* sp; const int* degrees;
    const float* init_W; const float* init_b; const float* cent_emb;
    const float* db; const float* vbias;
    const float* Wq; const float* bq; const float* Wk; const float* bk;
    const float* Wv; const float* bv; const float* Wo; const float* bo;
    const float* W1; const float* b1; const float* W2; const float* b2;
    float* h; unsigned short* hn; unsigned short* o; unsigned short* qkv;
    float* Bg; unsigned short* Wqkv_t; unsigned short* Wo_t;
    unsigned short* W1_t; unsigned short* W2_t; float* bqkv;
    unsigned* cnt; float* out;
};

// ---------------- software grid barrier (monotone counter) ----------------
__device__ __forceinline__ void gridbar(unsigned* cnt, unsigned& target) {
    __syncthreads();
    if (threadIdx.x == 0) {
        __threadfence();
        __hip_atomic_fetch_add(cnt, 1u, __ATOMIC_RELEASE, __HIP_MEMORY_SCOPE_AGENT);
        target += NBLK;
        while (__hip_atomic_load(cnt, __ATOMIC_ACQUIRE, __HIP_MEMORY_SCOPE_AGENT) < target)
            __builtin_amdgcn_s_sleep(1);
    }
    __syncthreads();
}

__global__ void zero_bar(unsigned* cnt) { if (threadIdx.x == 0) *cnt = 0; }

// ---------------- prep tasks ----------------
__device__ __forceinline__ void prep_init(char* smem, const MP& p, int t) {
    int tid = threadIdx.x;
    if (t >= NT) {                       // build B block for graph t-NT
        int g = t - NT;
        float vb = p.vbias[0];
        for (int e = tid; e < 1024; e += 256) {
            int i = e >> 5, j = e & 31;
            float v;
            if (i == j) v = p.db[0];
            else if (i < NP && j < NP) {
                int s = p.sp[(size_t)(g * NP + i) * NORI + g * NP + j];
                v = p.db[s < 100 ? s : 100];
            } else v = vb;
            p.Bg[(size_t)g * 1024 + e] = v;
        }
        return;
    }
    int n = t;
    float* xs = (float*)smem;
    if (n < NORI && tid < NFEA) xs[tid] = p.x[(size_t)n * NFEA + tid];
    __syncthreads();
    int deg = p.degrees[n]; if (deg > 100) deg = 100;
    for (int d = tid; d < DIM; d += 256) {
        float v = p.cent_emb[(size_t)deg * DIM + d];
        if (n < NORI) {
            float acc = p.init_b[d];
            #pragma unroll
            for (int k = 0; k < NFEA; ++k) acc += xs[k] * p.init_W[(size_t)k * DIM + d];
            v += acc;
        }
        p.h[(size_t)n * DIM + d] = v;
    }
}

__device__ __forceinline__ void prep_qkv(char* smem, const MP& p, int t) {
    int tid = threadIdx.x;
    if (t >= 3072) {                     // bias part
        int idx = (t - 3072) * 256 + tid;
        if (idx < NLAY * 1536) {
            int l = idx / 1536, c = idx % 1536;
            int which = c >> 9, cc = c & 511;
            const float* b = (which == 0) ? p.bq : (which == 1) ? p.bk : p.bv;
            p.bqkv[idx] = b[(size_t)l * 512 + cc];
        }
        return;
    }
    int slice = t >> 5, tloc = t & 31;
    int dt = tloc >> 1, kt = tloc & 1;
    int l = slice / 24; int rem = slice % 24; int which = rem >> 3; int hh = rem & 7;
    const float* W = (which == 0) ? p.Wq : (which == 1) ? p.Wk : p.Wv;
    const float* in = W + (size_t)(l * 8 + hh) * DIM * DKH;
    float* tl = (float*)smem;            // [32][33]
    int tr = tid >> 5, tc = tid & 31;
    #pragma unroll
    for (int q = 0; q < 4; ++q)
        tl[(tr + q * 8) * 33 + tc] = in[(size_t)(dt * 32 + tr + q * 8) * DKH + kt * 32 + tc];
    __syncthreads();
    unsigned short* out = p.Wqkv_t +
        ((size_t)l * 1536 + which * 512 + hh * 64 + kt * 32) * DIM + dt * 32;
    #pragma unroll
    for (int q = 0; q < 4; ++q)
        out[(size_t)(tr + q * 8) * DIM + tc] = f2bf(tl[tc * 33 + tr + q * 8]);
}

__device__ __forceinline__ void prep_w_task(char* smem, const MP& p, int id) {
    int tid = threadIdx.x;
    const float* in; unsigned short* out; int R, C, l, rt, ct;
    if (id < 1024) {
        l = id >> 8; int t = id & 255; rt = t >> 4; ct = t & 15;
        in = p.Wo; out = p.Wo_t; R = 512; C = 512;
    } else if (id < 5120) {
        int t2 = id - 1024; l = t2 >> 10; int t = t2 & 1023; rt = t >> 6; ct = t & 63;
        in = p.W1; out = p.W1_t; R = 512; C = 2048;
    } else {
        int t2 = id - 5120; l = t2 >> 10; int t = t2 & 1023; rt = t >> 4; ct = t & 15;
        in = p.W2; out = p.W2_t; R = 2048; C = 512;
    }
    const float* ip = in + (size_t)l * R * C;
    unsigned short* op = out + (size_t)l * R * C;
    int r0 = rt * 32, c0 = ct * 32;
    float* tl = (float*)smem;            // [32][33]
    int tr = tid >> 5, tc = tid & 31;
    #pragma unroll
    for (int q = 0; q < 4; ++q)
        tl[(tr + q * 8) * 33 + tc] = ip[(size_t)(r0 + tr + q * 8) * C + c0 + tc];
    __syncthreads();
    #pragma unroll
    for (int q = 0; q < 4; ++q)
        op[(size_t)(c0 + tr + q * 8) * R + r0 + tc] = f2bf(tl[tc * 33 + tr + q * 8]);
}

// ---------------- layernorm row ----------------
__device__ __forceinline__ void ln_row(char* smem, const float* in,
                                       unsigned short* out, int n) {
    float* red = (float*)smem;
    int tid = threadIdx.x;
    const float* row = in + (size_t)n * DIM;
    float v0 = row[tid], v1 = row[tid + 256];
    float s = v0 + v1;
    float sq = v0 * v0 + v1 * v1;
    #pragma unroll
    for (int off = 32; off > 0; off >>= 1) {
        s  += __shfl_down(s, off);
        sq += __shfl_down(sq, off);
    }
    int wave = tid >> 6;
    if ((tid & 63) == 0) { red[wave] = s; red[4 + wave] = sq; }
    __syncthreads();
    float ts  = red[0] + red[1] + red[2] + red[3];
    float tsq = red[4] + red[5] + red[6] + red[7];
    float m   = ts * (1.0f / DIM);
    float var = tsq * (1.0f / DIM) - m * m;
    float inv = rsqrtf(var + 1e-5f);
    out[(size_t)n * DIM + tid]       = f2bf((v0 - m) * inv);
    out[(size_t)n * DIM + tid + 256] = f2bf((v1 - m) * inv);
    __syncthreads();
}

// ---------------- 64x64x64 bf16 MFMA GEMM tile ----------------
__device__ __forceinline__ void gemm_tile(
    char* smem, const unsigned short* A, const unsigned short* Bt,
    const float* bias, void* out, int Nfull, int K,
    int row0, int col0, int kbeg, int kslice, int splitk, int kz, int flags)
{
    unsigned short* Asl = (unsigned short*)smem;
    unsigned short* Bsl = Asl + 64 * 72;
    int tid = threadIdx.x;
    int wave = tid >> 6, lane = tid & 63;
    int quad = lane >> 4, m16 = lane & 15;
    int mw = (wave >> 1) * 32, nw = (wave & 1) * 32;
    floatx4 acc[2][2] = {};
    for (int k0 = kbeg; k0 < kbeg + kslice; k0 += 64) {
        #pragma unroll
        for (int q = 0; q < 2; ++q) {
            int idx = (q * 256 + tid) * 8;
            int r = idx >> 6, kk = idx & 63;
            *(float4*)(Asl + r * 72 + kk) =
                *(const float4*)(A + (size_t)(row0 + r) * K + k0 + kk);
            *(float4*)(Bsl + r * 72 + kk) =
                *(const float4*)(Bt + (size_t)(col0 + r) * K + k0 + kk);
        }
        __syncthreads();
        #pragma unroll
        for (int ks = 0; ks < 64; ks += 32) {
            short8 a[2], b[2];
            #pragma unroll
            for (int mi = 0; mi < 2; ++mi)
                a[mi] = *(const short8*)(Asl + (mw + mi * 16 + m16) * 72 + ks + quad * 8);
            #pragma unroll
            for (int ni = 0; ni < 2; ++ni)
                b[ni] = *(const short8*)(Bsl + (nw + ni * 16 + m16) * 72 + ks + quad * 8);
            #pragma unroll
            for (int mi = 0; mi < 2; ++mi)
                #pragma unroll
                for (int ni = 0; ni < 2; ++ni)
                    acc[mi][ni] = __builtin_amdgcn_mfma_f32_16x16x32_bf16(
                        a[mi], b[ni], acc[mi][ni], 0, 0, 0);
        }
        __syncthreads();
    }
    if (splitk == 1) {
        int do_relu = flags & 1, out_bf = flags & 2;
        #pragma unroll
        for (int mi = 0; mi < 2; ++mi) {
            #pragma unroll
            for (int ni = 0; ni < 2; ++ni) {
                int col = col0 + nw + ni * 16 + m16;
                float bval = bias[col];
                #pragma unroll
                for (int rr = 0; rr < 4; ++rr) {
                    int row = row0 + mw + mi * 16 + quad * 4 + rr;
                    float v = acc[mi][ni][rr] + bval;
                    if (do_relu) v = fmaxf(v, 0.0f);
                    if (out_bf) ((unsigned short*)out)[(size_t)row * Nfull + col] = f2bf(v);
                    else        ((float*)out)[(size_t)row * Nfull + col] = v;
                }
            }
        }
    } else {
        float* o = (float*)out;
        float bscale = (kz == 0) ? 1.0f : 0.0f;
        #pragma unroll
        for (int mi = 0; mi < 2; ++mi) {
            #pragma unroll
            for (int ni = 0; ni < 2; ++ni) {
                int col = col0 + nw + ni * 16 + m16;
                float bval = bias[col] * bscale;
                #pragma unroll
                for (int rr = 0; rr < 4; ++rr) {
                    int row = row0 + mw + mi * 16 + quad * 4 + rr;
                    atomicAdd(&o[(size_t)row * Nfull + col], acc[mi][ni][rr] + bval);
                }
            }
        }
    }
}

// ---------------- block-diagonal attention, one (graph, head) ----------------
__device__ __forceinline__ void attn_tile(char* smem, const unsigned short* qkv,
                                          const float* Bg, unsigned short* O, int t) {
    int g = t >> 3, hh = t & 7;
    float* Qs = (float*)smem;            // [32][65]
    float* Ks = Qs + 32 * 65;
    float* Vs = Ks + 32 * 65;
    float* S  = Vs + 32 * 65;            // [32][33]
    int tid = threadIdx.x;
    int i = tid >> 3;
    int c0 = (tid & 7) * 8;
    int gn = (i < NP) ? g * NP + i : NORI + g;
    const unsigned short* base = qkv + (size_t)gn * 1536 + hh * DKH;
    short8 qv = *(const short8*)(base + c0);
    short8 kv = *(const short8*)(base + 512 + c0);
    short8 vv = *(const short8*)(base + 1024 + c0);
    #pragma unroll
    for (int j = 0; j < 8; ++j) {
        Qs[i * 65 + c0 + j] = bf2f((unsigned short)qv[j]);
        Ks[i * 65 + c0 + j] = bf2f((unsigned short)kv[j]);
        Vs[i * 65 + c0 + j] = bf2f((unsigned short)vv[j]);
    }
    __syncthreads();
    const float scale = 0.125f;
    #pragma unroll
    for (int e = 0; e < 4; ++e) {
        int idx = tid + e * 256;
        int si = idx >> 5, sj = idx & 31;
        float dot = 0.0f;
        #pragma unroll
        for (int k = 0; k < DKH; ++k) dot += Qs[si * 65 + k] * Ks[sj * 65 + k];
        S[si * 33 + sj] = dot * scale + Bg[(size_t)g * 1024 + si * 32 + sj];
    }
    __syncthreads();
    if (tid < 32) {
        float mx = -1e30f;
        #pragma unroll
        for (int j = 0; j < 32; ++j) mx = fmaxf(mx, S[tid * 33 + j]);
        float sum = 0.0f;
        #pragma unroll
        for (int j = 0; j < 32; ++j) {
            float e = __expf(S[tid * 33 + j] - mx); S[tid * 33 + j] = e; sum += e;
        }
        float inv = 1.0f / sum;
        #pragma unroll
        for (int j = 0; j < 32; ++j) S[tid * 33 + j] *= inv;
    }
    __syncthreads();
    short8 ov;
    #pragma unroll
    for (int cc = 0; cc < 8; ++cc) {
        float acc = 0.0f;
        #pragma unroll
        for (int j = 0; j < 32; ++j) acc += S[i * 33 + j] * Vs[j * 65 + c0 + cc];
        ov[cc] = (short)f2bf(acc);
    }
    *(short8*)(O + (size_t)gn * DIM + hh * DKH + c0) = ov;
    __syncthreads();
}

// ---------------- tile-id decode with XCD swizzle ----------------
__device__ __forceinline__ void decode(int id, int Pp, int C, int& by, int& bx, int& bz) {
    if (Pp >= 8) {
        int xcd = id & 7, t = id >> 3, G = Pp >> 3;
        by = xcd + 8 * (t % G);
        int r2 = t / G;
        bx = r2 % C;
        bz = r2 / C;
    } else {
        by = id % Pp; int r2 = id / Pp; bx = r2 % C; bz = r2 / C;
    }
}

// ---------------- the megakernel ----------------
__global__ __launch_bounds__(256, 2) void mega(MP p) {
    __shared__ __align__(16) char smem[29312];
    const int nb = NBLK, bid = blockIdx.x, tid = threadIdx.x;
    unsigned target = 0;

    // stage 0: all prep (independent tasks)
    for (int t = bid; t < 2112 + 3096 + 9216; t += nb) {
        if (t < 2112)      prep_init(smem, p, t);
        else if (t < 5208) prep_qkv(smem, p, t - 2112);
        else               prep_w_task(smem, p, t - 5208);
        __syncthreads();
    }
    gridbar(p.cnt, target);

    unsigned short* ffnb = p.qkv;        // alias (R8-proven)
    for (int l = 0; l < NLAY; ++l) {
        bool last = (l == NLAY - 1);
        // LN(h) -> hn (all rows; last layer still needs all for K,V)
        for (int r = bid; r < NT; r += nb) ln_row(smem, p.h, p.hn, r);
        gridbar(p.cnt, target);
        // qkv = hn @ Wqkv^T + bqkv   (bf16 out; last: Q only for virt panel)
        {
            const unsigned short* Wt = p.Wqkv_t + (size_t)l * 1536 * DIM;
            const float* bb = p.bqkv + (size_t)l * 1536;
            for (int t = bid; t < 768; t += nb) {
                int by, bx, bz; decode(t, 32, 24, by, bx, bz);
                if (last && bx < 8 && by != 31) continue;
                gemm_tile(smem, p.hn, Wt, bb, p.qkv, 1536, DIM,
                          by * 64, bx * 64, 0, DIM, 1, 0, 2);
            }
        }
        gridbar(p.cnt, target);
        // attention (last layer: garbage Q rows produce unused finite rows)
        for (int t = bid; t < 512; t += nb) attn_tile(smem, p.qkv, p.Bg, p.o, t);
        gridbar(p.cnt, target);
        // h += o @ Wo^T + bo  (split-K atomics into residual h)
        {
            const unsigned short* Wt = p.Wo_t + (size_t)l * DIM * DIM;
            const float* bb = p.bo + (size_t)l * DIM;
            if (!last) {
                for (int t = bid; t < 512; t += nb) {
                    int by, bx, bz; decode(t, 32, 8, by, bx, bz);
                    gemm_tile(smem, p.o, Wt, bb, p.h, DIM, DIM,
                              by * 64, bx * 64, bz * 256, 256, 2, bz, 0);
                }
            } else {
                for (int t = bid; t < 64; t += nb) {
                    int by, bx, bz; decode(t, 1, 8, by, bx, bz);
                    gemm_tile(smem, p.o, Wt, bb, p.h, DIM, DIM,
                              NORI, bx * 64, bz * 64, 64, 8, bz, 0);
                }
            }
        }
        gridbar(p.cnt, target);
        // LN(h) -> hn (last layer: virt rows only)
        {
            int r0 = last ? NORI : 0, nr = last ? NG : NT;
            for (int r = bid; r < nr; r += nb) ln_row(smem, p.h, p.hn, r0 + r);
        }
        gridbar(p.cnt, target);
        // ffnb = relu(hn @ W1^T + b1)
        {
            const unsigned short* Wt = p.W1_t + (size_t)l * FFD * DIM;
            const float* bb = p.b1 + (size_t)l * FFD;
            if (!last) {
                for (int t = bid; t < 1024; t += nb) {
                    int by, bx, bz; decode(t, 32, 32, by, bx, bz);
                    gemm_tile(smem, p.hn, Wt, bb, ffnb, FFD, DIM,
                              by * 64, bx * 64, 0, DIM, 1, 0, 3);
                }
            } else {
                for (int t = bid; t < 32; t += nb) {
                    int by, bx, bz; decode(t, 1, 32, by, bx, bz);
                    gemm_tile(smem, p.hn, Wt, bb, ffnb, FFD, DIM,
                              NORI, bx * 64, 0, DIM, 1, 0, 3);
                }
            }
        }
        gridbar(p.cnt, target);
        // h += ffnb @ W2^T + b2  (split-K atomics)
        {
            const unsigned short* Wt = p.W2_t + (size_t)l * DIM * FFD;
            const float* bb = p.b2 + (size_t)l * DIM;
            if (!last) {
                for (int t = bid; t < 1024; t += nb) {
                    int by, bx, bz; decode(t, 32, 8, by, bx, bz);
                    gemm_tile(smem, ffnb, Wt, bb, p.h, DIM, FFD,
                              by * 64, bx * 64, bz * 512, 512, 4, bz, 0);
                }
            } else {
                for (int t = bid; t < 64; t += nb) {
                    int by, bx, bz; decode(t, 1, 8, by, bx, bz);
                    gemm_tile(smem, ffnb, Wt, bb, p.h, DIM, FFD,
                              NORI, bx * 64, bz * 256, 256, 8, bz, 0);
                }
            }
        }
        gridbar(p.cnt, target);
    }
    // copy h[virt] -> out (fp32)
    for (int i = bid * 256 + tid; i < NG * DIM; i += nb * 256)
        p.out[i] = p.h[(size_t)NORI * DIM + i];
}

// ---------------------------------------------------------------- launch
extern "C" void kernel_launch(void* const* d_in, const int* in_sizes, int n_in,
                              void* d_out, int out_size, void* d_ws, size_t ws_size,
                              hipStream_t stream)
{
    MP p;
    p.x        = (const float*)d_in[0];
    p.sp       = (const int*)d_in[1];
    p.degrees  = (const int*)d_in[3];
    p.init_W   = (const float*)d_in[4];
    p.init_b   = (const float*)d_in[5];
    p.cent_emb = (const float*)d_in[6];
    p.db       = (const float*)d_in[7];
    p.vbias    = (const float*)d_in[8];
    p.Wq       = (const float*)d_in[9];
    p.bq       = (const float*)d_in[10];
    p.Wk       = (const float*)d_in[11];
    p.bk       = (const float*)d_in[12];
    p.Wv       = (const float*)d_in[13];
    p.bv       = (const float*)d_in[14];
    p.Wo       = (const float*)d_in[15];
    p.bo       = (const float*)d_in[16];
    p.W1       = (const float*)d_in[17];
    p.b1       = (const float*)d_in[18];
    p.W2       = (const float*)d_in[19];
    p.b2       = (const float*)d_in[20];

    char* ws = (char*)d_ws;
    p.h      = (float*)ws;          ws += (size_t)NT * DIM * 4;
    p.hn     = (unsigned short*)ws; ws += (size_t)NT * DIM * 2;
    p.o      = (unsigned short*)ws; ws += (size_t)NT * DIM * 2;
    p.qkv    = (unsigned short*)ws; ws += (size_t)NT * FFD * 2;   // aliased qkv/ffnb
    p.Bg     = (float*)ws;          ws += (size_t)NG * 1024 * 4;
    p.Wqkv_t = (unsigned short*)ws; ws += (size_t)NLAY * 1536 * DIM * 2;
    p.Wo_t   = (unsigned short*)ws; ws += (size_t)NLAY * DIM * DIM * 2;
    p.W1_t   = (unsigned short*)ws; ws += (size_t)NLAY * FFD * DIM * 2;
    p.W2_t   = (unsigned short*)ws; ws += (size_t)NLAY * DIM * FFD * 2;
    p.bqkv   = (float*)ws;          ws += (size_t)NLAY * 1536 * 4;
    p.cnt    = (unsigned*)ws;       ws += 256;   // barrier counter (own cacheline)
    p.out    = (float*)d_out;

    zero_bar<<<1, 64, 0, stream>>>(p.cnt);
    mega<<<NBLK, 256, 0, stream>>>(p);
}

// Round 12
// 2064.368 us; speedup vs baseline: 1.1502x; 1.1502x over previous
//
#include <hip/hip_runtime.h>

// Graphormer encoder as ONE persistent megakernel (plain launch). R12: software
// grid barrier rebuilt as two-phase flag barrier (per-block slots + aggregator +
// broadcast) — R11's single-line counter serialized and cost ~2 ms.
// Stage bodies identical to R8's proven kernels. Attention block-diagonal.

#define NG   64
#define NP   31
#define NORI 1984
#define NT   2048
#define DIM  512
#define NHD  8
#define DKH  64
#define FFD  2048
#define NLAY 4
#define NFEA 32

#define NBLK 512
#define SLOTSTRIDE 32   // u32s per slot = 128 B

typedef __attribute__((ext_vector_type(8))) short short8;
typedef __attribute__((ext_vector_type(4))) float floatx4;

__device__ __forceinline__ unsigned short f2bf(float f) {
    union { float f; unsigned u; } v; v.f = f;
    unsigned r = v.u + 0x7fffu + ((v.u >> 16) & 1u);
    return (unsigned short)(r >> 16);
}
__device__ __forceinline__ float bf2f(unsigned short u) {
    union { unsigned u; float f; } v; v.u = ((unsigned)u) << 16;
    return v.f;
}

struct MP {
    const float* x; const int* sp; const int* degrees;
    const float* init_W; const float* init_b; const float* cent_emb;
    const float* db; const float* vbias;
    const float* Wq; const float* bq; const float* Wk; const float* bk;
    const float* Wv; const float* bv; const float* Wo; const float* bo;
    const float* W1; const float* b1; const float* W2; const float* b2;
    float* h; unsigned short* hn; unsigned short* o; unsigned short* qkv;
    float* Bg; unsigned short* Wqkv_t; unsigned short* Wo_t;
    unsigned short* W1_t; unsigned short* W2_t; float* bqkv;
    unsigned* slots; unsigned* bcast; float* out;
};

// ---------------- two-phase grid barrier ----------------
// Arrival: block b stores epoch to slots[b*SLOTSTRIDE] (own cacheline, no RMW).
// Block 0 scans all slots (parallel distinct-line reads), then releases epoch
// to bcast. Spinners poll only bcast with sleep backoff.
__device__ __forceinline__ void gridbar(const MP& p, unsigned& epoch) {
    __syncthreads();
    ++epoch;
    int bid = blockIdx.x, tid = threadIdx.x;
    if (bid == 0) {
        for (int s = tid; s < NBLK; s += 256) {
            if (s == 0) continue;
            while (__hip_atomic_load(&p.slots[s * SLOTSTRIDE], __ATOMIC_ACQUIRE,
                                     __HIP_MEMORY_SCOPE_AGENT) < epoch)
                __builtin_amdgcn_s_sleep(2);
        }
        __syncthreads();
        if (tid == 0)
            __hip_atomic_store(p.bcast, epoch, __ATOMIC_RELEASE,
                               __HIP_MEMORY_SCOPE_AGENT);
    } else {
        if (tid == 0) {
            __hip_atomic_store(&p.slots[bid * SLOTSTRIDE], epoch, __ATOMIC_RELEASE,
                               __HIP_MEMORY_SCOPE_AGENT);
            while (__hip_atomic_load(p.bcast, __ATOMIC_ACQUIRE,
                                     __HIP_MEMORY_SCOPE_AGENT) < epoch)
                __builtin_amdgcn_s_sleep(16);
        }
        __syncthreads();
    }
}

__global__ void zero_bar(unsigned* base, int n) {
    int i = blockIdx.x * 256 + threadIdx.x;
    if (i < n) base[i] = 0;
}

// ---------------- prep tasks ----------------
__device__ __forceinline__ void prep_init(char* smem, const MP& p, int t) {
    int tid = threadIdx.x;
    if (t >= NT) {                       // build B block for graph t-NT
        int g = t - NT;
        float vb = p.vbias[0];
        for (int e = tid; e < 1024; e += 256) {
            int i = e >> 5, j = e & 31;
            float v;
            if (i == j) v = p.db[0];
            else if (i < NP && j < NP) {
                int s = p.sp[(size_t)(g * NP + i) * NORI + g * NP + j];
                v = p.db[s < 100 ? s : 100];
            } else v = vb;
            p.Bg[(size_t)g * 1024 + e] = v;
        }
        return;
    }
    int n = t;
    float* xs = (float*)smem;
    if (n < NORI && tid < NFEA) xs[tid] = p.x[(size_t)n * NFEA + tid];
    __syncthreads();
    int deg = p.degrees[n]; if (deg > 100) deg = 100;
    for (int d = tid; d < DIM; d += 256) {
        float v = p.cent_emb[(size_t)deg * DIM + d];
        if (n < NORI) {
            float acc = p.init_b[d];
            #pragma unroll
            for (int k = 0; k < NFEA; ++k) acc += xs[k] * p.init_W[(size_t)k * DIM + d];
            v += acc;
        }
        p.h[(size_t)n * DIM + d] = v;
    }
}

__device__ __forceinline__ void prep_qkv(char* smem, const MP& p, int t) {
    int tid = threadIdx.x;
    if (t >= 3072) {                     // bias part
        int idx = (t - 3072) * 256 + tid;
        if (idx < NLAY * 1536) {
            int l = idx / 1536, c = idx % 1536;
            int which = c >> 9, cc = c & 511;
            const float* b = (which == 0) ? p.bq : (which == 1) ? p.bk : p.bv;
            p.bqkv[idx] = b[(size_t)l * 512 + cc];
        }
        return;
    }
    int slice = t >> 5, tloc = t & 31;
    int dt = tloc >> 1, kt = tloc & 1;
    int l = slice / 24; int rem = slice % 24; int which = rem >> 3; int hh = rem & 7;
    const float* W = (which == 0) ? p.Wq : (which == 1) ? p.Wk : p.Wv;
    const float* in = W + (size_t)(l * 8 + hh) * DIM * DKH;
    float* tl = (float*)smem;            // [32][33]
    int tr = tid >> 5, tc = tid & 31;
    #pragma unroll
    for (int q = 0; q < 4; ++q)
        tl[(tr + q * 8) * 33 + tc] = in[(size_t)(dt * 32 + tr + q * 8) * DKH + kt * 32 + tc];
    __syncthreads();
    unsigned short* out = p.Wqkv_t +
        ((size_t)l * 1536 + which * 512 + hh * 64 + kt * 32) * DIM + dt * 32;
    #pragma unroll
    for (int q = 0; q < 4; ++q)
        out[(size_t)(tr + q * 8) * DIM + tc] = f2bf(tl[tc * 33 + tr + q * 8]);
}

__device__ __forceinline__ void prep_w_task(char* smem, const MP& p, int id) {
    int tid = threadIdx.x;
    const float* in; unsigned short* out; int R, C, l, rt, ct;
    if (id < 1024) {
        l = id >> 8; int t = id & 255; rt = t >> 4; ct = t & 15;
        in = p.Wo; out = p.Wo_t; R = 512; C = 512;
    } else if (id < 5120) {
        int t2 = id - 1024; l = t2 >> 10; int t = t2 & 1023; rt = t >> 6; ct = t & 63;
        in = p.W1; out = p.W1_t; R = 512; C = 2048;
    } else {
        int t2 = id - 5120; l = t2 >> 10; int t = t2 & 1023; rt = t >> 4; ct = t & 15;
        in = p.W2; out = p.W2_t; R = 2048; C = 512;
    }
    const float* ip = in + (size_t)l * R * C;
    unsigned short* op = out + (size_t)l * R * C;
    int r0 = rt * 32, c0 = ct * 32;
    float* tl = (float*)smem;            // [32][33]
    int tr = tid >> 5, tc = tid & 31;
    #pragma unroll
    for (int q = 0; q < 4; ++q)
        tl[(tr + q * 8) * 33 + tc] = ip[(size_t)(r0 + tr + q * 8) * C + c0 + tc];
    __syncthreads();
    #pragma unroll
    for (int q = 0; q < 4; ++q)
        op[(size_t)(c0 + tr + q * 8) * R + r0 + tc] = f2bf(tl[tc * 33 + tr + q * 8]);
}

// ---------------- layernorm row ----------------
__device__ __forceinline__ void ln_row(char* smem, const float* in,
                                       unsigned short* out, int n) {
    float* red = (float*)smem;
    int tid = threadIdx.x;
    const float* row = in + (size_t)n * DIM;
    float v0 = row[tid], v1 = row[tid + 256];
    float s = v0 + v1;
    float sq = v0 * v0 + v1 * v1;
    #pragma unroll
    for (int off = 32; off > 0; off >>= 1) {
        s  += __shfl_down(s, off);
        sq += __shfl_down(sq, off);
    }
    int wave = tid >> 6;
    if ((tid & 63) == 0) { red[wave] = s; red[4 + wave] = sq; }
    __syncthreads();
    float ts  = red[0] + red[1] + red[2] + red[3];
    float tsq = red[4] + red[5] + red[6] + red[7];
    float m   = ts * (1.0f / DIM);
    float var = tsq * (1.0f / DIM) - m * m;
    float inv = rsqrtf(var + 1e-5f);
    out[(size_t)n * DIM + tid]       = f2bf((v0 - m) * inv);
    out[(size_t)n * DIM + tid + 256] = f2bf((v1 - m) * inv);
    __syncthreads();
}

// ---------------- 64x64x64 bf16 MFMA GEMM tile ----------------
__device__ __forceinline__ void gemm_tile(
    char* smem, const unsigned short* A, const unsigned short* Bt,
    const float* bias, void* out, int Nfull, int K,
    int row0, int col0, int kbeg, int kslice, int splitk, int kz, int flags)
{
    unsigned short* Asl = (unsigned short*)smem;
    unsigned short* Bsl = Asl + 64 * 72;
    int tid = threadIdx.x;
    int wave = tid >> 6, lane = tid & 63;
    int quad = lane >> 4, m16 = lane & 15;
    int mw = (wave >> 1) * 32, nw = (wave & 1) * 32;
    floatx4 acc[2][2] = {};
    for (int k0 = kbeg; k0 < kbeg + kslice; k0 += 64) {
        #pragma unroll
        for (int q = 0; q < 2; ++q) {
            int idx = (q * 256 + tid) * 8;
            int r = idx >> 6, kk = idx & 63;
            *(float4*)(Asl + r * 72 + kk) =
                *(const float4*)(A + (size_t)(row0 + r) * K + k0 + kk);
            *(float4*)(Bsl + r * 72 + kk) =
                *(const float4*)(Bt + (size_t)(col0 + r) * K + k0 + kk);
        }
        __syncthreads();
        #pragma unroll
        for (int ks = 0; ks < 64; ks += 32) {
            short8 a[2], b[2];
            #pragma unroll
            for (int mi = 0; mi < 2; ++mi)
                a[mi] = *(const short8*)(Asl + (mw + mi * 16 + m16) * 72 + ks + quad * 8);
            #pragma unroll
            for (int ni = 0; ni < 2; ++ni)
                b[ni] = *(const short8*)(Bsl + (nw + ni * 16 + m16) * 72 + ks + quad * 8);
            #pragma unroll
            for (int mi = 0; mi < 2; ++mi)
                #pragma unroll
                for (int ni = 0; ni < 2; ++ni)
                    acc[mi][ni] = __builtin_amdgcn_mfma_f32_16x16x32_bf16(
                        a[mi], b[ni], acc[mi][ni], 0, 0, 0);
        }
        __syncthreads();
    }
    if (splitk == 1) {
        int do_relu = flags & 1, out_bf = flags & 2;
        #pragma unroll
        for (int mi = 0; mi < 2; ++mi) {
            #pragma unroll
            for (int ni = 0; ni < 2; ++ni) {
                int col = col0 + nw + ni * 16 + m16;
                float bval = bias[col];
                #pragma unroll
                for (int rr = 0; rr < 4; ++rr) {
                    int row = row0 + mw + mi * 16 + quad * 4 + rr;
                    float v = acc[mi][ni][rr] + bval;
                    if (do_relu) v = fmaxf(v, 0.0f);
                    if (out_bf) ((unsigned short*)out)[(size_t)row * Nfull + col] = f2bf(v);
                    else        ((float*)out)[(size_t)row * Nfull + col] = v;
                }
            }
        }
    } else {
        float* o = (float*)out;
        float bscale = (kz == 0) ? 1.0f : 0.0f;
        #pragma unroll
        for (int mi = 0; mi < 2; ++mi) {
            #pragma unroll
            for (int ni = 0; ni < 2; ++ni) {
                int col = col0 + nw + ni * 16 + m16;
                float bval = bias[col] * bscale;
                #pragma unroll
                for (int rr = 0; rr < 4; ++rr) {
                    int row = row0 + mw + mi * 16 + quad * 4 + rr;
                    atomicAdd(&o[(size_t)row * Nfull + col], acc[mi][ni][rr] + bval);
                }
            }
        }
    }
}

// ---------------- block-diagonal attention, one (graph, head) ----------------
__device__ __forceinline__ void attn_tile(char* smem, const unsigned short* qkv,
                                          const float* Bg, unsigned short* O, int t) {
    int g = t >> 3, hh = t & 7;
    float* Qs = (float*)smem;            // [32][65]
    float* Ks = Qs + 32 * 65;
    float* Vs = Ks + 32 * 65;
    float* S  = Vs + 32 * 65;            // [32][33]
    int tid = threadIdx.x;
    int i = tid >> 3;
    int c0 = (tid & 7) * 8;
    int gn = (i < NP) ? g * NP + i : NORI + g;
    const unsigned short* base = qkv + (size_t)gn * 1536 + hh * DKH;
    short8 qv = *(const short8*)(base + c0);
    short8 kv = *(const short8*)(base + 512 + c0);
    short8 vv = *(const short8*)(base + 1024 + c0);
    #pragma unroll
    for (int j = 0; j < 8; ++j) {
        Qs[i * 65 + c0 + j] = bf2f((unsigned short)qv[j]);
        Ks[i * 65 + c0 + j] = bf2f((unsigned short)kv[j]);
        Vs[i * 65 + c0 + j] = bf2f((unsigned short)vv[j]);
    }
    __syncthreads();
    const float scale = 0.125f;
    #pragma unroll
    for (int e = 0; e < 4; ++e) {
        int idx = tid + e * 256;
        int si = idx >> 5, sj = idx & 31;
        float dot = 0.0f;
        #pragma unroll
        for (int k = 0; k < DKH; ++k) dot += Qs[si * 65 + k] * Ks[sj * 65 + k];
        S[si * 33 + sj] = dot * scale + Bg[(size_t)g * 1024 + si * 32 + sj];
    }
    __syncthreads();
    if (tid < 32) {
        float mx = -1e30f;
        #pragma unroll
        for (int j = 0; j < 32; ++j) mx = fmaxf(mx, S[tid * 33 + j]);
        float sum = 0.0f;
        #pragma unroll
        for (int j = 0; j < 32; ++j) {
            float e = __expf(S[tid * 33 + j] - mx); S[tid * 33 + j] = e; sum += e;
        }
        float inv = 1.0f / sum;
        #pragma unroll
        for (int j = 0; j < 32; ++j) S[tid * 33 + j] *= inv;
    }
    __syncthreads();
    short8 ov;
    #pragma unroll
    for (int cc = 0; cc < 8; ++cc) {
        float acc = 0.0f;
        #pragma unroll
        for (int j = 0; j < 32; ++j) acc += S[i * 33 + j] * Vs[j * 65 + c0 + cc];
        ov[cc] = (short)f2bf(acc);
    }
    *(short8*)(O + (size_t)gn * DIM + hh * DKH + c0) = ov;
    __syncthreads();
}

// ---------------- tile-id decode with XCD swizzle ----------------
__device__ __forceinline__ void decode(int id, int Pp, int C, int& by, int& bx, int& bz) {
    if (Pp >= 8) {
        int xcd = id & 7, t = id >> 3, G = Pp >> 3;
        by = xcd + 8 * (t % G);
        int r2 = t / G;
        bx = r2 % C;
        bz = r2 / C;
    } else {
        by = id % Pp; int r2 = id / Pp; bx = r2 % C; bz = r2 / C;
    }
}

// ---------------- the megakernel ----------------
__global__ __launch_bounds__(256, 2) void mega(MP p) {
    __shared__ __align__(16) char smem[29312];
    const int nb = NBLK, bid = blockIdx.x, tid = threadIdx.x;
    unsigned epoch = 0;

    // stage 0: all prep (independent tasks)
    for (int t = bid; t < 2112 + 3096 + 9216; t += nb) {
        if (t < 2112)      prep_init(smem, p, t);
        else if (t < 5208) prep_qkv(smem, p, t - 2112);
        else               prep_w_task(smem, p, t - 5208);
        __syncthreads();
    }
    gridbar(p, epoch);

    unsigned short* ffnb = p.qkv;        // alias (R8-proven)
    for (int l = 0; l < NLAY; ++l) {
        bool last = (l == NLAY - 1);
        // LN(h) -> hn (all rows; last layer still needs all for K,V)
        for (int r = bid; r < NT; r += nb) ln_row(smem, p.h, p.hn, r);
        gridbar(p, epoch);
        // qkv = hn @ Wqkv^T + bqkv   (bf16 out; last: Q only for virt panel)
        {
            const unsigned short* Wt = p.Wqkv_t + (size_t)l * 1536 * DIM;
            const float* bb = p.bqkv + (size_t)l * 1536;
            for (int t = bid; t < 768; t += nb) {
                int by, bx, bz; decode(t, 32, 24, by, bx, bz);
                if (last && bx < 8 && by != 31) continue;
                gemm_tile(smem, p.hn, Wt, bb, p.qkv, 1536, DIM,
                          by * 64, bx * 64, 0, DIM, 1, 0, 2);
            }
        }
        gridbar(p, epoch);
        // attention (last layer: garbage Q rows produce unused finite rows)
        for (int t = bid; t < 512; t += nb) attn_tile(smem, p.qkv, p.Bg, p.o, t);
        gridbar(p, epoch);
        // h += o @ Wo^T + bo  (split-K atomics into residual h)
        {
            const unsigned short* Wt = p.Wo_t + (size_t)l * DIM * DIM;
            const float* bb = p.bo + (size_t)l * DIM;
            if (!last) {
                for (int t = bid; t < 512; t += nb) {
                    int by, bx, bz; decode(t, 32, 8, by, bx, bz);
                    gemm_tile(smem, p.o, Wt, bb, p.h, DIM, DIM,
                              by * 64, bx * 64, bz * 256, 256, 2, bz, 0);
                }
            } else {
                for (int t = bid; t < 64; t += nb) {
                    int by, bx, bz; decode(t, 1, 8, by, bx, bz);
                    gemm_tile(smem, p.o, Wt, bb, p.h, DIM, DIM,
                              NORI, bx * 64, bz * 64, 64, 8, bz, 0);
                }
            }
        }
        gridbar(p, epoch);
        // LN(h) -> hn (last layer: virt rows only)
        {
            int r0 = last ? NORI : 0, nr = last ? NG : NT;
            for (int r = bid; r < nr; r += nb) ln_row(smem, p.h, p.hn, r0 + r);
        }
        gridbar(p, epoch);
        // ffnb = relu(hn @ W1^T + b1)
        {
            const unsigned short* Wt = p.W1_t + (size_t)l * FFD * DIM;
            const float* bb = p.b1 + (size_t)l * FFD;
            if (!last) {
                for (int t = bid; t < 1024; t += nb) {
                    int by, bx, bz; decode(t, 32, 32, by, bx, bz);
                    gemm_tile(smem, p.hn, Wt, bb, ffnb, FFD, DIM,
                              by * 64, bx * 64, 0, DIM, 1, 0, 3);
                }
            } else {
                for (int t = bid; t < 32; t += nb) {
                    int by, bx, bz; decode(t, 1, 32, by, bx, bz);
                    gemm_tile(smem, p.hn, Wt, bb, ffnb, FFD, DIM,
                              NORI, bx * 64, 0, DIM, 1, 0, 3);
                }
            }
        }
        gridbar(p, epoch);
        // h += ffnb @ W2^T + b2  (split-K atomics)
        {
            const unsigned short* Wt = p.W2_t + (size_t)l * DIM * FFD;
            const float* bb = p.b2 + (size_t)l * DIM;
            if (!last) {
                for (int t = bid; t < 1024; t += nb) {
                    int by, bx, bz; decode(t, 32, 8, by, bx, bz);
                    gemm_tile(smem, ffnb, Wt, bb, p.h, DIM, FFD,
                              by * 64, bx * 64, bz * 512, 512, 4, bz, 0);
                }
            } else {
                for (int t = bid; t < 64; t += nb) {
                    int by, bx, bz; decode(t, 1, 8, by, bx, bz);
                    gemm_tile(smem, ffnb, Wt, bb, p.h, DIM, FFD,
                              NORI, bx * 64, bz * 256, 256, 8, bz, 0);
                }
            }
        }
        gridbar(p, epoch);
    }
    // copy h[virt] -> out (fp32)
    for (int i = bid * 256 + tid; i < NG * DIM; i += nb * 256)
        p.out[i] = p.h[(size_t)NORI * DIM + i];
}

// ---------------------------------------------------------------- launch
extern "C" void kernel_launch(void* const* d_in, const int* in_sizes, int n_in,
                              void* d_out, int out_size, void* d_ws, size_t ws_size,
                              hipStream_t stream)
{
    MP p;
    p.x        = (const float*)d_in[0];
    p.sp       = (const int*)d_in[1];
    p.degrees  = (const int*)d_in[3];
    p.init_W   = (const float*)d_in[4];
    p.init_b   = (const float*)d_in[5];
    p.cent_emb = (const float*)d_in[6];
    p.db       = (const float*)d_in[7];
    p.vbias    = (const float*)d_in[8];
    p.Wq       = (const float*)d_in[9];
    p.bq       = (const float*)d_in[10];
    p.Wk       = (const float*)d_in[11];
    p.bk       = (const float*)d_in[12];
    p.Wv       = (const float*)d_in[13];
    p.bv       = (const float*)d_in[14];
    p.Wo       = (const float*)d_in[15];
    p.bo       = (const float*)d_in[16];
    p.W1       = (const float*)d_in[17];
    p.b1       = (const float*)d_in[18];
    p.W2       = (const float*)d_in[19];
    p.b2       = (const float*)d_in[20];

    char* ws = (char*)d_ws;
    p.h      = (float*)ws;          ws += (size_t)NT * DIM * 4;
    p.hn     = (unsigned short*)ws; ws += (size_t)NT * DIM * 2;
    p.o      = (unsigned short*)ws; ws += (size_t)NT * DIM * 2;
    p.qkv    = (unsigned short*)ws; ws += (size_t)NT * FFD * 2;   // aliased qkv/ffnb
    p.Bg     = (float*)ws;          ws += (size_t)NG * 1024 * 4;
    p.Wqkv_t = (unsigned short*)ws; ws += (size_t)NLAY * 1536 * DIM * 2;
    p.Wo_t   = (unsigned short*)ws; ws += (size_t)NLAY * DIM * DIM * 2;
    p.W1_t   = (unsigned short*)ws; ws += (size_t)NLAY * FFD * DIM * 2;
    p.W2_t   = (unsigned short*)ws; ws += (size_t)NLAY * DIM * FFD * 2;
    p.bqkv   = (float*)ws;          ws += (size_t)NLAY * 1536 * 4;
    p.slots  = (unsigned*)ws;       ws += (size_t)NBLK * SLOTSTRIDE * 4;
    p.bcast  = (unsigned*)ws;       ws += 128;
    p.out    = (float*)d_out;

    int nbar = NBLK * SLOTSTRIDE + 32;   // slots + bcast line, in u32s
    zero_bar<<<(nbar + 255) / 256, 256, 0, stream>>>(p.slots, nbar);
    mega<<<NBLK, 256, 0, stream>>>(p);
}